// Round 1
// baseline (611.123 us; speedup 1.0000x reference)
//
#include <hip/hip_runtime.h>
#include <hip/hip_bf16.h>
#include <math.h>

#define H_DIM 4096
#define N_EXP 64
#define N_TOK 16384
#define KB    128     // k-chunk staged in LDS (floats)
#define TM    8       // tokens per wave
#define NWAVE 4       // waves per block

// ---------------- logits GEMM: lane = expert, wave = 8 tokens ----------------
__global__ __launch_bounds__(256, 2)
void router_logits_kernel(const float* __restrict__ x,
                          const float* __restrict__ W,
                          const float* __restrict__ bias,
                          float* __restrict__ logits) {
    __shared__ float4 wlds[(KB / 4) * N_EXP];  // 32*64 float4 = 32 KB

    const int tid  = threadIdx.x;
    const int lane = tid & 63;                 // expert id
    const int wid  = __builtin_amdgcn_readfirstlane(tid >> 6);
    const int tok0 = blockIdx.x * (NWAVE * TM) + wid * TM;

    float acc[TM];
#pragma unroll
    for (int t = 0; t < TM; ++t) acc[t] = 0.0f;

    for (int kc = 0; kc < H_DIM; kc += KB) {
        __syncthreads();
        // stage W[0..64)[kc..kc+KB) into LDS, swizzled:
        //   float4 unit index u = jg*64 + (e ^ (jg & 7))
#pragma unroll
        for (int i = 0; i < (KB / 4) * N_EXP / 256; ++i) {   // 8 iters
            int idx = tid + i * 256;                          // 0..2047
            int se  = idx >> 5;                               // expert
            int sj  = idx & 31;                               // float4 group
            float4 v = *(const float4*)(W + se * H_DIM + kc + sj * 4);
            wlds[sj * 64 + (se ^ (sj & 7))] = v;
        }
        __syncthreads();

        float c[TM];
#pragma unroll
        for (int t = 0; t < TM; ++t) c[t] = 0.0f;

#pragma unroll 4
        for (int jg = 0; jg < KB / 4; ++jg) {
            float4 w = wlds[jg * 64 + (lane ^ (jg & 7))];
            const float* xbase = x + (size_t)tok0 * H_DIM + kc + jg * 4;
#pragma unroll
            for (int t = 0; t < TM; ++t) {
                float4 xv = *(const float4*)(xbase + (size_t)t * H_DIM);
                c[t] = fmaf(w.x, xv.x, c[t]);
                c[t] = fmaf(w.y, xv.y, c[t]);
                c[t] = fmaf(w.z, xv.z, c[t]);
                c[t] = fmaf(w.w, xv.w, c[t]);
            }
        }
#pragma unroll
        for (int t = 0; t < TM; ++t) acc[t] += c[t];
    }

    float bv = bias[lane];
#pragma unroll
    for (int t = 0; t < TM; ++t)
        logits[(size_t)(tok0 + t) * N_EXP + lane] = acc[t] + bv;
}

// ---------------- softmax + top-2 + renorm weights ----------------
__global__ __launch_bounds__(256)
void topk_kernel(const float* __restrict__ logits,
                 float* __restrict__ wout,
                 float* __restrict__ iout) {
    int n = blockIdx.x * 256 + threadIdx.x;
    if (n >= N_TOK) return;

    float l[64];
    const float4* lp = (const float4*)(logits + (size_t)n * N_EXP);
#pragma unroll
    for (int i = 0; i < 16; ++i) {
        float4 v = lp[i];
        l[4 * i + 0] = v.x; l[4 * i + 1] = v.y;
        l[4 * i + 2] = v.z; l[4 * i + 3] = v.w;
    }

    // top-2 on logits (softmax is monotonic); strict '>' keeps lowest index on ties
    float v1 = -INFINITY, v2 = -INFINITY;
    int   i1 = 0, i2 = 0;
#pragma unroll
    for (int i = 0; i < 64; ++i) {
        float li = l[i];
        if (li > v1)      { v2 = v1; i2 = i1; v1 = li; i1 = i; }
        else if (li > v2) { v2 = li; i2 = i; }
    }

    float Z = 0.0f;
#pragma unroll
    for (int i = 0; i < 64; ++i) Z += expf(l[i] - v1);

    float p1 = 1.0f / Z;             // exp(v1-v1)/Z
    float p2 = expf(v2 - v1) / Z;

    // softmax over [p1, p2] (p1 >= p2)
    float t  = expf(p2 - p1);
    float w0 = 1.0f / (1.0f + t);
    float w1 = t / (1.0f + t);

    wout[2 * n + 0] = w0;
    wout[2 * n + 1] = w1;
    iout[2 * n + 0] = (float)i1;
    iout[2 * n + 1] = (float)i2;
}

// ---------------- expert mask [E][K][N] as 0.0/1.0 floats ----------------
__global__ __launch_bounds__(256)
void mask_kernel(const float* __restrict__ iout,
                 float* __restrict__ mask) {
    int gid = blockIdx.x * 256 + threadIdx.x;      // 0 .. 2*64*16384-1
    int n   = gid & (N_TOK - 1);
    int ek  = gid >> 14;                            // e*2 + k
    float idxf = iout[(size_t)n * 2 + (ek & 1)];
    mask[gid] = (idxf == (float)(ek >> 1)) ? 1.0f : 0.0f;
}

extern "C" void kernel_launch(void* const* d_in, const int* in_sizes, int n_in,
                              void* d_out, int out_size, void* d_ws, size_t ws_size,
                              hipStream_t stream) {
    const float* x  = (const float*)d_in[0];
    const float* W  = (const float*)d_in[1];
    const float* b  = (const float*)d_in[2];

    float* out    = (float*)d_out;
    float* logits = out;                          // N_TOK * 64
    float* wout   = logits + (size_t)N_TOK * 64;  // N_TOK * 2
    float* iout   = wout   + (size_t)N_TOK * 2;   // N_TOK * 2
    float* mask   = iout   + (size_t)N_TOK * 2;   // 64 * 2 * N_TOK

    router_logits_kernel<<<N_TOK / (NWAVE * TM), 256, 0, stream>>>(x, W, b, logits);
    topk_kernel<<<N_TOK / 256, 256, 0, stream>>>(logits, wout, iout);
    mask_kernel<<<(N_EXP * 2 * N_TOK) / 256, 256, 0, stream>>>(iout, mask);
}

// Round 2
// 277.733 us; speedup vs baseline: 2.2004x; 2.2004x over previous
//
#include <hip/hip_runtime.h>
#include <hip/hip_bf16.h>
#include <math.h>

#define H_DIM 4096
#define N_EXP 64
#define N_TOK 16384
#define KB    128     // k-chunk staged in LDS (floats)
#define TM    8       // tokens per wave
#define NWAVE 4       // waves per block
#define TB    (TM * NWAVE)   // 32 tokens per block

// ---------------- logits GEMM: lane = expert, wave = 8 tokens ----------------
// Both W and x staged in LDS. x global loads are coalesced; x LDS reads are
// wave-broadcast (free); W LDS reads use the XOR swizzle (0 conflicts measured).
__global__ __launch_bounds__(256)
void router_logits_kernel(const float* __restrict__ x,
                          const float* __restrict__ W,
                          const float* __restrict__ bias,
                          float* __restrict__ logits) {
    __shared__ float4 wlds[(KB / 4) * N_EXP];   // 32*64 float4 = 32 KB
    __shared__ float4 xlds[TB][KB / 4];         // 32*32 float4 = 16 KB

    const int tid   = threadIdx.x;
    const int lane  = tid & 63;                 // expert id
    const int wid   = __builtin_amdgcn_readfirstlane(tid >> 6);
    const int tok0b = blockIdx.x * TB;          // block's first token
    const int trow0 = wid * TM;                 // wave's first token row in xlds

    float acc[TM];
#pragma unroll
    for (int t = 0; t < TM; ++t) acc[t] = 0.0f;

    for (int kc = 0; kc < H_DIM; kc += KB) {
        __syncthreads();
        // ---- stage W[0..64)[kc..kc+KB) swizzled: u = sj*64 + (se ^ (sj&7))
#pragma unroll
        for (int i = 0; i < (KB / 4) * N_EXP / 256; ++i) {   // 8 iters
            int idx = tid + i * 256;
            int se  = idx >> 5;                               // expert
            int sj  = idx & 31;                               // float4 group
            float4 v = *(const float4*)(W + (size_t)se * H_DIM + kc + sj * 4);
            wlds[sj * 64 + (se ^ (sj & 7))] = v;
        }
        // ---- stage x[tok0b..tok0b+TB)[kc..kc+KB), coalesced 16B/lane
#pragma unroll
        for (int i = 0; i < TB * (KB / 4) / 256; ++i) {      // 4 iters
            int idx = tid + i * 256;
            int row = idx >> 5;                               // token row
            int col = idx & 31;                               // float4 group
            xlds[row][col] =
                *(const float4*)(x + (size_t)(tok0b + row) * H_DIM + kc + col * 4);
        }
        __syncthreads();

#pragma unroll 4
        for (int jg = 0; jg < KB / 4; ++jg) {
            float4 w = wlds[jg * 64 + (lane ^ (jg & 7))];
#pragma unroll
            for (int t = 0; t < TM; ++t) {
                float4 xv = xlds[trow0 + t][jg];   // broadcast across lanes
                acc[t] = fmaf(w.x, xv.x, acc[t]);
                acc[t] = fmaf(w.y, xv.y, acc[t]);
                acc[t] = fmaf(w.z, xv.z, acc[t]);
                acc[t] = fmaf(w.w, xv.w, acc[t]);
            }
        }
    }

    float bv = bias[lane];
#pragma unroll
    for (int t = 0; t < TM; ++t)
        logits[(size_t)(tok0b + trow0 + t) * N_EXP + lane] = acc[t] + bv;
}

// ---------------- softmax + top-2 + renorm weights ----------------
__global__ __launch_bounds__(256)
void topk_kernel(const float* __restrict__ logits,
                 float* __restrict__ wout,
                 float* __restrict__ iout) {
    int n = blockIdx.x * 256 + threadIdx.x;
    if (n >= N_TOK) return;

    float l[64];
    const float4* lp = (const float4*)(logits + (size_t)n * N_EXP);
#pragma unroll
    for (int i = 0; i < 16; ++i) {
        float4 v = lp[i];
        l[4 * i + 0] = v.x; l[4 * i + 1] = v.y;
        l[4 * i + 2] = v.z; l[4 * i + 3] = v.w;
    }

    // top-2 on logits (softmax is monotonic); strict '>' keeps lowest index on ties
    float v1 = -INFINITY, v2 = -INFINITY;
    int   i1 = 0, i2 = 0;
#pragma unroll
    for (int i = 0; i < 64; ++i) {
        float li = l[i];
        if (li > v1)      { v2 = v1; i2 = i1; v1 = li; i1 = i; }
        else if (li > v2) { v2 = li; i2 = i; }
    }

    float Z = 0.0f;
#pragma unroll
    for (int i = 0; i < 64; ++i) Z += expf(l[i] - v1);

    float p1 = 1.0f / Z;             // exp(v1-v1)/Z
    float p2 = expf(v2 - v1) / Z;

    // softmax over [p1, p2] (p1 >= p2)
    float t  = expf(p2 - p1);
    float w0 = 1.0f / (1.0f + t);
    float w1 = t / (1.0f + t);

    wout[2 * n + 0] = w0;
    wout[2 * n + 1] = w1;
    iout[2 * n + 0] = (float)i1;
    iout[2 * n + 1] = (float)i2;
}

// ---------------- expert mask [E][K][N] as 0.0/1.0 floats ----------------
__global__ __launch_bounds__(256)
void mask_kernel(const float* __restrict__ iout,
                 float* __restrict__ mask) {
    int gid = blockIdx.x * 256 + threadIdx.x;      // 0 .. 2*64*16384-1
    int n   = gid & (N_TOK - 1);
    int ek  = gid >> 14;                            // e*2 + k
    float idxf = iout[(size_t)n * 2 + (ek & 1)];
    mask[gid] = (idxf == (float)(ek >> 1)) ? 1.0f : 0.0f;
}

extern "C" void kernel_launch(void* const* d_in, const int* in_sizes, int n_in,
                              void* d_out, int out_size, void* d_ws, size_t ws_size,
                              hipStream_t stream) {
    const float* x  = (const float*)d_in[0];
    const float* W  = (const float*)d_in[1];
    const float* b  = (const float*)d_in[2];

    float* out    = (float*)d_out;
    float* logits = out;                          // N_TOK * 64
    float* wout   = logits + (size_t)N_TOK * 64;  // N_TOK * 2
    float* iout   = wout   + (size_t)N_TOK * 2;   // N_TOK * 2
    float* mask   = iout   + (size_t)N_TOK * 2;   // 64 * 2 * N_TOK

    router_logits_kernel<<<N_TOK / TB, 256, 0, stream>>>(x, W, b, logits);
    topk_kernel<<<N_TOK / 256, 256, 0, stream>>>(logits, wout, iout);
    mask_kernel<<<(N_EXP * 2 * N_TOK) / 256, 256, 0, stream>>>(iout, mask);
}